// Round 7
// baseline (451.519 us; speedup 1.0000x reference)
//
#include <hip/hip_runtime.h>
#include <hip/hip_bf16.h>
#include <hip/hip_fp16.h>
#include <stdint.h>

typedef __bf16 bf16;
typedef __bf16 bf16x8 __attribute__((ext_vector_type(8)));
typedef _Float16 f16x8 __attribute__((ext_vector_type(8)));
typedef float f32x4 __attribute__((ext_vector_type(4)));

#define NSEQ 2048
#define CDIM 512

// ---- ws layout (bytes) ----
#define WS_FLAGS   0         // int[3]: x dtype, w dtype, const 0
#define WS_BPB     1024
#define WS_WPB     4096
#define WS_WEC     532480    // We_q, We_k (512x1536 bf16 each)
#define WS_WECT    3678208   // We_v^T (1536x512 bf16)
#define WS_W1T     5251072
#define WS_W3R     6823936
#define WS_BASE    11542528  // adaptive region: Sb | slotA | (optional) xb

__device__ __forceinline__ float rdf(const void* p, long i, int f) {
  if (f == 1) return ((const float*)p)[i];
  if (f == 2) return (float)((const _Float16*)p)[i];
  return (float)((const bf16*)p)[i];
}

__device__ __forceinline__ void gl_lds16(const bf16* g, bf16* l) {
  __builtin_amdgcn_global_load_lds(
      (__attribute__((address_space(1))) void*)g,
      (__attribute__((address_space(3))) void*)l, 16, 0, 0);
}

__device__ __forceinline__ void stage_one(const void* gb, long eoff, int dt,
                                          bf16* ldst)
{
  if (dt == 1) {
    const float* g = (const float*)gb + eoff;
    const float4 u0 = *(const float4*)g;
    const float4 u1 = *(const float4*)(g + 4);
    bf16x8 t;
    t[0]=(bf16)u0.x; t[1]=(bf16)u0.y; t[2]=(bf16)u0.z; t[3]=(bf16)u0.w;
    t[4]=(bf16)u1.x; t[5]=(bf16)u1.y; t[6]=(bf16)u1.z; t[7]=(bf16)u1.w;
    *(bf16x8*)ldst = t;
  } else if (dt == 2) {
    const f16x8 h = *(const f16x8*)((const _Float16*)gb + eoff);
    bf16x8 t;
#pragma unroll
    for (int j = 0; j < 8; ++j) t[j] = (bf16)(float)h[j];
    *(bf16x8*)ldst = t;
  } else {
    gl_lds16((const bf16*)gb + eoff, ldst);
  }
}

// 3-way dtype detect (0 bf16, 1 f32, 2 fp16); flags[2] <- 0.
__global__ __launch_bounds__(256)
void detect2(const unsigned short* __restrict__ a,
             const unsigned short* __restrict__ b, int* __restrict__ flags)
{
  const unsigned short* p = blockIdx.x ? b : a;
  __shared__ int chi, clo;
  if (threadIdx.x == 0) { chi = 0; clo = 0; }
  __syncthreads();
  int hi = 0, lo = 0;
  for (int i = threadIdx.x; i < 4096; i += 256) {
    const int e = (p[i] >> 7) & 0xff;
    hi += (e >= 141);
    lo += (e >= 1 && e <= 110);
  }
  atomicAdd(&chi, hi);
  atomicAdd(&clo, lo);
  __syncthreads();
  if (threadIdx.x == 0) {
    flags[blockIdx.x] = (chi > 8) ? 1 : ((clo > 100) ? 2 : 0);
    if (blockIdx.x == 0) flags[2] = 0;
  }
}

// x (any dtype) -> canonical bf16 copy, 8 elem/thread vectorized
__global__ __launch_bounds__(256)
void cvt_x8(const void* __restrict__ x, const int* __restrict__ flag,
            bf16* __restrict__ xb)
{
  const long i8 = (long)blockIdx.x * 256 + threadIdx.x;
  const int f = *flag;
  bf16x8 t;
  if (f == 1) {
    const float4* g = (const float4*)x + i8 * 2;
    const float4 u0 = g[0], u1 = g[1];
    t[0]=(bf16)u0.x; t[1]=(bf16)u0.y; t[2]=(bf16)u0.z; t[3]=(bf16)u0.w;
    t[4]=(bf16)u1.x; t[5]=(bf16)u1.y; t[6]=(bf16)u1.z; t[7]=(bf16)u1.w;
  } else if (f == 2) {
    const f16x8 h = ((const f16x8*)x)[i8];
#pragma unroll
    for (int j = 0; j < 8; ++j) t[j] = (bf16)(float)h[j];
  } else {
    t = ((const bf16x8*)x)[i8];
  }
  ((bf16x8*)xb)[i8] = t;
}

// ---------------------------------------------------------------------------
// Old 128^2 gemm (kept for weight prep, At, U, and non-canonical fallback)
// C[m][n] = sum_k A[m][k] * B[n][k]   (K-contiguous operands, bf16 MFMA)
template<int AX3, int BX3, int EPI, int ZMODE>
__global__ __launch_bounds__(256)
void gemm_bt(const void* __restrict__ Abase, const void* __restrict__ Bbase,
             void* __restrict__ Cbase, const bf16* __restrict__ bias,
             const int* __restrict__ xflag, int zxb,
             int M, int Nd, int K, int lda, int ldb, int ldc,
             long zsA, long zsB, long zsC)
{
  __shared__ bf16 As[128 * 32];
  __shared__ bf16 Bs[128 * 32];
  const int z = blockIdx.z;
  const int xdt = (AX3 || BX3) ? *xflag : 0;
  long Aoff, Boff; char* CB;
  if (ZMODE == 1) {
    const int g = z / 3, t = z - g * 3;
    Aoff = (long)z * 262144;
    Boff = (long)g * 262144;
    CB = (char*)Cbase + ((long)g * (512 * 1536) + t * 512) * 2;
  } else {
    Aoff = AX3 ? 0 : (long)z * zsA;
    Boff = BX3 ? 0 : (long)z * zsB;
    CB = (char*)Cbase + (long)z * zsC * (EPI == 2 ? 4 : 2);
  }
  const int m0 = blockIdx.y * 128;
  const int n0 = blockIdx.x * 128;
  const int tid = threadIdx.x;
  const int lane = tid & 63;
  const int w = tid >> 6;
  const int wr = (w >> 1) * 64;
  const int wc = (w & 1) * 64;

  f32x4 acc[4][4];
  const f32x4 zero = {0.f, 0.f, 0.f, 0.f};
#pragma unroll
  for (int i = 0; i < 4; ++i)
#pragma unroll
    for (int j = 0; j < 4; ++j) acc[i][j] = zero;

  for (int k0 = 0; k0 < K; k0 += 32) {
#pragma unroll
    for (int it = 0; it < 2; ++it) {
      const int f  = (it * 256 + tid) * 16;
      const int r  = f >> 6;
      const int cb = (f & 63) >> 1;
      long ea, eb;
      if (AX3) {
        const int tau = k0 >> 9;
        ea = (long)(z + zxb) * zsA +
             (long)((m0 + r + tau - 1) & (NSEQ - 1)) * CDIM + (k0 & 511) + cb;
      } else {
        ea = Aoff + (long)(m0 + r) * lda + k0 + cb;
      }
      stage_one(Abase, ea, AX3 ? xdt : 0, (bf16*)((char*)As + f));
      if (BX3) {
        const int tau = k0 >> 9;
        eb = (long)(z + zxb) * zsB +
             (long)((n0 + r + tau - 1) & (NSEQ - 1)) * CDIM + (k0 & 511) + cb;
      } else {
        eb = Boff + (long)(n0 + r) * ldb + k0 + cb;
      }
      stage_one(Bbase, eb, BX3 ? xdt : 0, (bf16*)((char*)Bs + f));
    }
    __syncthreads();

    const int qb = (lane >> 4) * 16;
    const int fr = lane & 15;
    bf16x8 af[4], bfr[4];
#pragma unroll
    for (int i = 0; i < 4; ++i)
      af[i] = *(const bf16x8*)((const char*)As + (wr + i * 16 + fr) * 64 + qb);
#pragma unroll
    for (int j = 0; j < 4; ++j)
      bfr[j] = *(const bf16x8*)((const char*)Bs + (wc + j * 16 + fr) * 64 + qb);
#pragma unroll
    for (int i = 0; i < 4; ++i)
#pragma unroll
      for (int j = 0; j < 4; ++j)
        acc[i][j] = __builtin_amdgcn_mfma_f32_16x16x32_bf16(af[i], bfr[j], acc[i][j], 0, 0, 0);
    __syncthreads();
  }

  const int qa4 = (lane >> 4) * 4;
  const int cn = lane & 15;
#pragma unroll
  for (int i = 0; i < 4; ++i) {
#pragma unroll
    for (int j = 0; j < 4; ++j) {
      const int gn = n0 + wc + j * 16 + cn;
      const float bv = (EPI == 2) ? (float)bias[gn] : 0.f;
#pragma unroll
      for (int r = 0; r < 4; ++r) {
        const long gm = m0 + wr + i * 16 + qa4 + r;
        if (EPI == 2) ((float*)CB)[gm * ldc + gn] = acc[i][j][r] + bv;
        else          ((bf16*)CB)[gm * ldc + gn] = (bf16)acc[i][j][r];
      }
    }
  }
}

// ---------------------------------------------------------------------------
// Fragment-order staging of a 256x32 bf16 operand tile (2 gl_lds/thread).
// LDS slot l of each 16-row group holds (row l&15, k-chunk l>>4) -> every
// fragment ds_read_b128 is base + lane*16 (contiguous 1 KiB wave read, 0
// bank conflicts); global source stays 64B-per-row coalesced.
template<int X3>
__device__ __forceinline__ void stage32(const bf16* __restrict__ gb, long zoff,
                                        int r0, int k0, int ld,
                                        char* ldsb, int tid)
{
#pragma unroll
  for (int is = 0; is < 2; ++is) {
    const int c = is * 512 + tid;
    const int g = c >> 6;
    const int l = c & 63;
    const int r = g * 16 + (l & 15);
    const int kb = l >> 4;
    long e;
    if (X3) {
      const int tau = k0 >> 9;
      const int rg = (r0 + r + tau - 1) & (NSEQ - 1);
      e = zoff + (long)rg * CDIM + ((k0 & 511) + kb * 8);
    } else {
      e = zoff + (long)(r0 + r) * ld + k0 + kb * 8;
    }
    gl_lds16(gb + e, (bf16*)(ldsb + c * 16));
  }
}

// ---------------------------------------------------------------------------
// R2 kernel: 256^2, BK=32, 64 KiB static LDS double-buffer (FALLBACK path).
template<int AX3, int BX3, int EPI>
__global__ __launch_bounds__(512)
void gemm8(const bf16* __restrict__ Ab, const bf16* __restrict__ Bb,
           void* __restrict__ Cbase, const bf16* __restrict__ bias,
           int zxb, int M, int Nd, int K, int lda, int ldb, int ldc,
           long zsA, long zsB, long zsC)
{
  __shared__ char smem[65536];
  const int z = blockIdx.z;
  const long Aoff = (long)(AX3 ? (z + zxb) : z) * zsA;
  const long Boff = (long)(BX3 ? (z + zxb) : z) * zsB;
  char* CB = (char*)Cbase + (long)z * zsC * (EPI == 2 ? 4 : 2);
  const int m0 = blockIdx.y * 256;
  const int n0 = blockIdx.x * 256;
  const int tid = threadIdx.x;
  const int lane = tid & 63;
  const int w = tid >> 6, wm = w >> 2, wn = w & 3;
  const int fro = lane * 16;

  f32x4 acc[8][4];
  const f32x4 zero = {0.f, 0.f, 0.f, 0.f};
#pragma unroll
  for (int i = 0; i < 8; ++i)
#pragma unroll
    for (int j = 0; j < 4; ++j) acc[i][j] = zero;

  const int KT = K >> 5;
  stage32<AX3>(Ab, Aoff, m0, 0, lda, smem, tid);
  stage32<BX3>(Bb, Boff, n0, 0, ldb, smem + 16384, tid);
  __syncthreads();

  for (int T = 0; T < KT; ++T) {
    const int cur = T & 1;
    const char* sA = smem + cur * 32768;
    const char* sB = sA + 16384;
    if (T + 1 < KT) {
      char* nb = smem + (cur ^ 1) * 32768;
      const int k1 = (T + 1) << 5;
      stage32<AX3>(Ab, Aoff, m0, k1, lda, nb, tid);
      stage32<BX3>(Bb, Boff, n0, k1, ldb, nb + 16384, tid);
    }
    bf16x8 bfr[4];
#pragma unroll
    for (int j = 0; j < 4; ++j)
      bfr[j] = *(const bf16x8*)(sB + (wn * 4 + j) * 1024 + fro);
#pragma unroll
    for (int h = 0; h < 2; ++h) {
      bf16x8 af[4];
#pragma unroll
      for (int i2 = 0; i2 < 4; ++i2)
        af[i2] = *(const bf16x8*)(sA + (wm * 8 + h * 4 + i2) * 1024 + fro);
      __builtin_amdgcn_s_setprio(1);
#pragma unroll
      for (int i2 = 0; i2 < 4; ++i2)
#pragma unroll
        for (int j = 0; j < 4; ++j)
          acc[h * 4 + i2][j] = __builtin_amdgcn_mfma_f32_16x16x32_bf16(
              af[i2], bfr[j], acc[h * 4 + i2][j], 0, 0, 0);
      __builtin_amdgcn_s_setprio(0);
      if (h == 0) __builtin_amdgcn_s_barrier();
    }
    __syncthreads();
  }

  const int lr = lane & 15, lk = lane >> 4;
#pragma unroll
  for (int i = 0; i < 8; ++i) {
#pragma unroll
    for (int j = 0; j < 4; ++j) {
      const int gn = n0 + wn * 64 + j * 16 + lr;
      const float bv = (EPI == 2) ? (float)bias[gn] : 0.f;
#pragma unroll
      for (int r = 0; r < 4; ++r) {
        const long gm = m0 + wm * 128 + i * 16 + lk * 4 + r;
        if (EPI == 2) ((float*)CB)[gm * ldc + gn] = acc[i][j][r] + bv;
        else          ((bf16*)CB)[gm * ldc + gn] = (bf16)acc[i][j][r];
      }
    }
  }
}

// ---------------------------------------------------------------------------
// gemm8e: 256^2 tile, BK=32, 5 x 32 KiB ring buffers (160 KiB dynamic LDS),
// DEPTH-4 counted-vmcnt pipeline + dual-barrier phase lock:
//   tile T: wait vmcnt(12) <- tile T landed; tiles T+1..T+3 (12 loads) fly
//           s_barrier      <- collective: everyone past tile T-1's reads
//           issue tile T+4 into ring slot (T+4)%5 (== slot of T-1, free)
//           bfr reads + {af half, setprio'd 16 MFMA} x2
//           s_barrier      <- phase lock (R3's measured-good ingredient)
// vmcnt never drains mid-loop; ~4 tiles (~12k cy) of load cover; waves stay
// phase-locked so the DS and MFMA pipes alternate coherently across waves.
template<int AX3, int BX3, int EPI>
__global__ __launch_bounds__(512)
void gemm8e(const bf16* __restrict__ Ab, const bf16* __restrict__ Bb,
            void* __restrict__ Cbase, const bf16* __restrict__ bias,
            int zxb, int M, int Nd, int K, int lda, int ldb, int ldc,
            long zsA, long zsB, long zsC)
{
  extern __shared__ char smem[];   // 5 x 32768
  // bijective XCD swizzle (m204)
  const int gx = gridDim.x, gy = gridDim.y;
  const int total = gx * gy * gridDim.z;
  const int lin = blockIdx.x + gx * (blockIdx.y + gy * blockIdx.z);
  const int q = total >> 3, r = total & 7;
  const int xcd = lin & 7, kq = lin >> 3;
  int swz = (xcd < r ? xcd * (q + 1) : r * (q + 1) + (xcd - r) * q) + kq;
  const int ny = swz % gy; swz /= gy;
  const int nx = swz % gx;
  const int z  = swz / gx;

  const long Aoff = (long)(AX3 ? (z + zxb) : z) * zsA;
  const long Boff = (long)(BX3 ? (z + zxb) : z) * zsB;
  char* CB = (char*)Cbase + (long)z * zsC * (EPI == 2 ? 4 : 2);
  const int m0 = ny * 256;
  const int n0 = nx * 256;
  const int tid = threadIdx.x;
  const int lane = tid & 63;
  const int w = tid >> 6, wm = w >> 2, wn = w & 3;   // 2M x 4N waves, 128x64
  const int fro = lane * 16;

  f32x4 acc[8][4];
  const f32x4 zero = {0.f, 0.f, 0.f, 0.f};
#pragma unroll
  for (int i = 0; i < 8; ++i)
#pragma unroll
    for (int j = 0; j < 4; ++j) acc[i][j] = zero;

  const int KT = K >> 5;   // >= 16 for all uses

  // prologue: stage tiles 0..3 (16 loads/thread in flight)
#pragma unroll
  for (int t = 0; t < 4; ++t) {
    if (t < KT) {
      stage32<AX3>(Ab, Aoff, m0, t << 5, lda, smem + t * 32768, tid);
      stage32<BX3>(Bb, Boff, n0, t << 5, ldb, smem + t * 32768 + 16384, tid);
    }
  }

  int sl = 0, sl4 = 4;   // T % 5 and (T+4) % 5 (no divide)
  for (int T = 0; T < KT; ++T) {
    const int rem = KT - 1 - T;
    if (rem >= 3)      asm volatile("s_waitcnt vmcnt(12)" ::: "memory");
    else if (rem == 2) asm volatile("s_waitcnt vmcnt(8)" ::: "memory");
    else if (rem == 1) asm volatile("s_waitcnt vmcnt(4)" ::: "memory");
    else               asm volatile("s_waitcnt vmcnt(0)" ::: "memory");
    __builtin_amdgcn_s_barrier();

    if (T + 4 < KT) {
      char* nb = smem + sl4 * 32768;
      const int k4 = (T + 4) << 5;
      stage32<AX3>(Ab, Aoff, m0, k4, lda, nb, tid);
      stage32<BX3>(Bb, Boff, n0, k4, ldb, nb + 16384, tid);
    }

    const char* sA = smem + sl * 32768;
    const char* sB = sA + 16384;
    bf16x8 bfr[4];
#pragma unroll
    for (int j = 0; j < 4; ++j)
      bfr[j] = *(const bf16x8*)(sB + (wn * 4 + j) * 1024 + fro);
#pragma unroll
    for (int h = 0; h < 2; ++h) {
      bf16x8 af[4];
#pragma unroll
      for (int i2 = 0; i2 < 4; ++i2)
        af[i2] = *(const bf16x8*)(sA + (wm * 8 + h * 4 + i2) * 1024 + fro);
      __builtin_amdgcn_s_setprio(1);
#pragma unroll
      for (int i2 = 0; i2 < 4; ++i2)
#pragma unroll
        for (int j = 0; j < 4; ++j)
          acc[h * 4 + i2][j] = __builtin_amdgcn_mfma_f32_16x16x32_bf16(
              af[i2], bfr[j], acc[h * 4 + i2][j], 0, 0, 0);
      __builtin_amdgcn_s_setprio(0);
    }
    __builtin_amdgcn_s_barrier();   // phase lock
    sl  = (sl  == 4) ? 0 : sl + 1;
    sl4 = (sl4 == 4) ? 0 : sl4 + 1;
  }

  const int lr = lane & 15, lk = lane >> 4;
#pragma unroll
  for (int i = 0; i < 8; ++i) {
#pragma unroll
    for (int j = 0; j < 4; ++j) {
      const int gn = n0 + wn * 64 + j * 16 + lr;
      const float bv = (EPI == 2) ? (float)bias[gn] : 0.f;
#pragma unroll
      for (int r2 = 0; r2 < 4; ++r2) {
        const long gm = m0 + wm * 128 + i * 16 + lk * 4 + r2;
        if (EPI == 2) ((float*)CB)[gm * ldc + gn] = acc[i][j][r2] + bv;
        else          ((bf16*)CB)[gm * ldc + gn] = (bf16)acc[i][j][r2];
      }
    }
  }
}

// ---------------------------------------------------------------------------
// w1t[g][a][b] = w1_g[b][a]; w3r[g*3+t][o][i] = w3_g[o][i][t]; wp/bp canonical.
__global__ __launch_bounds__(256)
void repack(const void* __restrict__ w1q, const void* __restrict__ w3q,
            const void* __restrict__ w1k, const void* __restrict__ w3k,
            const void* __restrict__ w1v, const void* __restrict__ w3v,
            const void* __restrict__ wp, const void* __restrict__ bpr,
            const int* __restrict__ flag,
            bf16* __restrict__ w1t, bf16* __restrict__ w3r,
            bf16* __restrict__ wpb, bf16* __restrict__ bpb)
{
  const int isf = *flag;
  const int g = blockIdx.z;
  const void* w1 = (g == 0) ? w1q : (g == 1) ? w1k : w1v;
  const void* w3 = (g == 0) ? w3q : (g == 1) ? w3k : w3v;
  const int idx = blockIdx.x * 256 + threadIdx.x;
  const int o = idx >> 9, c = idx & 511;
  w1t[g * 262144 + idx] = (bf16)rdf(w1, (long)c * 512 + o, isf);
#pragma unroll
  for (int t = 0; t < 3; ++t)
    w3r[(g * 3 + t) * 262144 + idx] = (bf16)rdf(w3, ((long)o * 512 + c) * 3 + t, isf);
  if (g == 0) {
    wpb[idx] = (bf16)rdf(wp, idx, isf);
    if (idx < 512) bpb[idx] = (bf16)rdf(bpr, idx, isf);
  }
}

// Column softmax over d on At[b][d][c] (scale 1/512), split into two
// 128-d-slice passes for 4x block parallelism. P[z][slice][c] = (m, l).
__global__ __launch_bounds__(256)
void softmax_p1(const bf16* __restrict__ S, float2* __restrict__ P)
{
  const int z = blockIdx.z;
  const int c = blockIdx.x * 256 + threadIdx.x;
  const int d0 = blockIdx.y * 128;
  const bf16* s = S + (long)z * 262144 + c;
  const float sc = 1.0f / 512.0f;
  float m = -3.4e38f, l = 0.f;
  for (int d = d0; d < d0 + 128; ++d) {
    const float v = (float)s[d * 512] * sc;
    const float nm = fmaxf(m, v);
    l = l * __expf(m - nm) + __expf(v - nm);
    m = nm;
  }
  P[((long)z * 4 + blockIdx.y) * 512 + c] = make_float2(m, l);
}

__global__ __launch_bounds__(256)
void softmax_p2(bf16* __restrict__ S, const float2* __restrict__ P)
{
  const int z = blockIdx.z;
  const int c = blockIdx.x * 256 + threadIdx.x;
  const int d0 = blockIdx.y * 128;
  float m = -3.4e38f, l = 0.f;
#pragma unroll
  for (int i = 0; i < 4; ++i) {
    const float2 p = P[((long)z * 4 + i) * 512 + c];
    const float nm = fmaxf(m, p.x);
    l = l * __expf(m - nm) + p.y * __expf(p.x - nm);
    m = nm;
  }
  const float inv = 1.0f / l;
  bf16* s = S + (long)z * 262144 + c;
  const float sc = 1.0f / 512.0f;
  for (int d = d0; d < d0 + 128; ++d) {
    const float v = (float)s[d * 512] * sc;
    s[d * 512] = (bf16)(__expf(v - m) * inv);
  }
}

extern "C" void kernel_launch(void* const* d_in, const int* in_sizes, int n_in,
                              void* d_out, int out_size, void* d_ws, size_t ws_size,
                              hipStream_t stream)
{
  // ---- resolve input roles from in_sizes (robust to ordering) ----
  long smax = -1, smin = (long)1 << 62;
  for (int i = 0; i < n_in; ++i) {
    const long s = in_sizes[i];
    if (s > smax) smax = s;
    if (s < smin) smin = s;
  }
  long s3 = -1;
  for (int i = 0; i < n_in; ++i) {
    const long s = in_sizes[i];
    if (s < smax && s > s3) s3 = s;
  }
  int xi = -1, bi = -1, w1i[8], n1 = 0, w3i[8], n3 = 0;
  for (int i = 0; i < n_in; ++i) {
    const long s = in_sizes[i];
    if (s == smax && xi < 0) xi = i;
    else if (s == smin && bi < 0) bi = i;
    else if (s == s3) { if (n3 < 8) w3i[n3++] = i; }
    else             { if (n1 < 8) w1i[n1++] = i; }
  }
  const void *x, *w1q, *w3q, *w1k, *w3k, *w1v, *w3v, *wp, *bp;
  if (xi >= 0 && bi >= 0 && n1 >= 4 && n3 >= 3) {
    x = d_in[xi]; bp = d_in[bi];
    w1q = d_in[w1i[0]]; w1k = d_in[w1i[1]]; w1v = d_in[w1i[2]]; wp = d_in[w1i[3]];
    w3q = d_in[w3i[0]]; w3k = d_in[w3i[1]]; w3v = d_in[w3i[2]];
  } else {
    x = d_in[0]; w1q = d_in[1]; w3q = d_in[2]; w1k = d_in[3]; w3k = d_in[4];
    w1v = d_in[5]; w3v = d_in[6]; wp = d_in[7]; bp = d_in[8];
  }
  float* out = (float*)d_out;  // reference output dtype = float32

  char* ws = (char*)d_ws;
  int*  flags = (int*)(ws + WS_FLAGS);
  bf16* bpb  = (bf16*)(ws + WS_BPB);
  bf16* wpb  = (bf16*)(ws + WS_WPB);
  bf16* wec  = (bf16*)(ws + WS_WEC);
  bf16* wecT = (bf16*)(ws + WS_WECT);
  bf16* w1t  = (bf16*)(ws + WS_W1T);
  bf16* w3r  = (bf16*)(ws + WS_W3R);

  // ---- adaptive: batch chunk NB + optional bf16-x staging copy ----
  int NB = 16, conv = 1;
  while (NB >= 1 && WS_BASE + (size_t)NB * 2621440 + 33554432 > ws_size) NB >>= 1;
  if (NB == 0) {
    conv = 0; NB = 16;
    while (NB > 1 && WS_BASE + (size_t)NB * 2621440 > ws_size) NB >>= 1;
  }
  bf16* Sb    = (bf16*)(ws + WS_BASE);
  bf16* slotA = (bf16*)(ws + WS_BASE + (size_t)NB * 524288);
  bf16* U     = slotA;
  bf16* Wfin  = slotA + (size_t)NB * 262144;
  bf16* xb    = (bf16*)(ws + WS_BASE + (size_t)NB * 2621440);
  float2* Pp  = (float2*)slotA;   // softmax partials: free while Q consumed

  const dim3 blk(256, 1, 1);
  const dim3 blk8(512, 1, 1);

  // opt-in to 160 KiB dynamic LDS for gemm8e; graceful fallback if refused
  bool oke = true;
  {
    hipError_t e;
    e = hipFuncSetAttribute(reinterpret_cast<const void*>(&gemm8e<0, 1, 0>),
                            hipFuncAttributeMaxDynamicSharedMemorySize, 163840);
    oke = oke && (e == hipSuccess);
    e = hipFuncSetAttribute(reinterpret_cast<const void*>(&gemm8e<0, 0, 0>),
                            hipFuncAttributeMaxDynamicSharedMemorySize, 163840);
    oke = oke && (e == hipSuccess);
    e = hipFuncSetAttribute(reinterpret_cast<const void*>(&gemm8e<1, 0, 2>),
                            hipFuncAttributeMaxDynamicSharedMemorySize, 163840);
    oke = oke && (e == hipSuccess);
  }

  // 1. dtype detect
  detect2<<<dim3(2, 1, 1), blk, 0, stream>>>(
      (const unsigned short*)x, (const unsigned short*)w1q, flags);

  // 2. canonical bf16 x copy (keeps the global_load_lds fast path)
  const void* xu = x;
  const int* xflag = flags;
  if (conv) {
    cvt_x8<<<dim3(8192, 1, 1), blk, 0, stream>>>(x, flags, xb);
    xu = xb;
    xflag = flags + 2;  // const 0 -> bf16 async staging
  }

  // 3. weights: repack + effective conv weights
  repack<<<dim3(1024, 1, 3), blk, 0, stream>>>(w1q, w3q, w1k, w3k, w1v, w3v,
                                               wp, bp, flags + 1,
                                               w1t, w3r, wpb, bpb);
  gemm_bt<0, 0, 0, 1><<<dim3(4, 4, 6), blk, 0, stream>>>(
      w3r, w1t, wec, nullptr, nullptr, 0, 512, 512, 512, 512, 512, 1536, 0, 0, 0);
  gemm_bt<0, 0, 0, 0><<<dim3(4, 4, 3), blk, 0, stream>>>(
      w1t + 2 * 262144, w3r + 6 * 262144, wecT, nullptr, nullptr, 0,
      512, 512, 512, 512, 512, 512, 0, 262144, 262144);

  // 4. attention pipeline, batch-chunked
  for (int b0 = 0; b0 < 16; b0 += NB) {
    char* outc = (char*)out + (size_t)b0 * 2048 * 512 * 4;
    if (conv) {
      // QK merged: [1024][2048] bf16 per batch parks in this chunk's f32 out
      // region (4 MB each, exact fit). Overwritten by 'out' only after At.
      bf16* QKc = (bf16*)outc;
      if (oke) {
        gemm8e<0, 1, 0><<<dim3(8, 4, NB), blk8, 163840, stream>>>(
            wec, (const bf16*)xu, QKc, nullptr, b0,
            1024, 2048, 1536, 1536, 0, 2048,
            0, (long)NSEQ * CDIM, (long)1024 * 2048);
      } else {
        gemm8<0, 1, 0><<<dim3(8, 4, NB), blk8, 0, stream>>>(
            wec, (const bf16*)xu, QKc, nullptr, b0,
            1024, 2048, 1536, 1536, 0, 2048,
            0, (long)NSEQ * CDIM, (long)1024 * 2048);
      }
      gemm_bt<0, 0, 0, 0><<<dim3(4, 4, NB), blk, 0, stream>>>(      // At[d][c]
          QKc + (long)512 * 2048, QKc, Sb, nullptr, nullptr, 0,
          512, 512, 2048, 2048, 2048, 512,
          (long)1024 * 2048, (long)1024 * 2048, (long)512 * 512);
      softmax_p1<<<dim3(2, 4, NB), blk, 0, stream>>>(Sb, Pp);
      softmax_p2<<<dim3(2, 4, NB), blk, 0, stream>>>(Sb, Pp);
      gemm_bt<0, 0, 0, 0><<<dim3(4, 4, NB), blk, 0, stream>>>(      // U[o][d]
          wpb, Sb, U, nullptr, nullptr, 0, 512, 512, 512, 512, 512, 512,
          0, (long)512 * 512, (long)512 * 512);
      if (oke) {
        gemm8e<0, 0, 0><<<dim3(6, 2, NB), blk8, 163840, stream>>>(  // Wfin[o][k]
            U, wecT, Wfin, nullptr, 0, 512, 1536, 512, 512, 512, 1536,
            (long)512 * 512, 0, (long)512 * 1536);
        gemm8e<1, 0, 2><<<dim3(2, 8, NB), blk8, 163840, stream>>>(  // out f32+bias
            (const bf16*)xu, Wfin, outc, bpb, b0,
            2048, 512, 1536, 0, 1536, 512,
            (long)NSEQ * CDIM, (long)512 * 1536, (long)2048 * 512);
      } else {
        gemm8<0, 0, 0><<<dim3(6, 2, NB), blk8, 0, stream>>>(
            U, wecT, Wfin, nullptr, 0, 512, 1536, 512, 512, 512, 1536,
            (long)512 * 512, 0, (long)512 * 1536);
        gemm8<1, 0, 2><<<dim3(2, 8, NB), blk8, 0, stream>>>(
            (const bf16*)xu, Wfin, outc, bpb, b0,
            2048, 512, 1536, 0, 1536, 512,
            (long)NSEQ * CDIM, (long)512 * 1536, (long)2048 * 512);
      }
    } else {
      // fallback: original 128^2 path with inline dtype conversion
      bf16* Kc = (bf16*)outc;
      gemm_bt<0, 1, 0, 0><<<dim3(16, 4, NB), blk, 0, stream>>>(     // Q[c][n]
          wec, xu, slotA, nullptr, xflag, b0, 512, 2048, 1536, 1536, 0, 2048,
          0, (long)NSEQ * CDIM, (long)512 * 2048);
      gemm_bt<0, 1, 0, 0><<<dim3(16, 4, NB), blk, 0, stream>>>(     // K[d][n]
          wec + 512 * 1536, xu, Kc, nullptr, xflag, b0, 512, 2048, 1536, 1536, 0, 2048,
          0, (long)NSEQ * CDIM, (long)512 * 2048);
      gemm_bt<0, 0, 0, 0><<<dim3(4, 4, NB), blk, 0, stream>>>(      // At[d][c]
          Kc, slotA, Sb, nullptr, nullptr, 0, 512, 512, 2048, 2048, 2048, 512,
          (long)512 * 2048, (long)512 * 2048, (long)512 * 512);
      softmax_p1<<<dim3(2, 4, NB), blk, 0, stream>>>(Sb, Pp);
      softmax_p2<<<dim3(2, 4, NB), blk, 0, stream>>>(Sb, Pp);
      gemm_bt<0, 0, 0, 0><<<dim3(4, 4, NB), blk, 0, stream>>>(      // U[o][d]
          wpb, Sb, U, nullptr, nullptr, 0, 512, 512, 512, 512, 512, 512,
          0, (long)512 * 512, (long)512 * 512);
      gemm_bt<0, 0, 0, 0><<<dim3(12, 4, NB), blk, 0, stream>>>(     // Wfin[o][k]
          U, wecT, Wfin, nullptr, nullptr, 0, 512, 1536, 512, 512, 512, 1536,
          (long)512 * 512, 0, (long)512 * 1536);
      gemm_bt<1, 0, 2, 0><<<dim3(4, 16, NB), blk, 0, stream>>>(     // out[n][o] f32+bias
          xu, Wfin, outc, bpb, xflag, b0,
          2048, 512, 1536, 0, 1536, 512,
          (long)NSEQ * CDIM, (long)512 * 1536, (long)2048 * 512);
    }
  }
}

// Round 9
// 420.933 us; speedup vs baseline: 1.0727x; 1.0727x over previous
//
#include <hip/hip_runtime.h>
#include <hip/hip_bf16.h>
#include <hip/hip_fp16.h>
#include <stdint.h>

typedef __bf16 bf16;
typedef __bf16 bf16x8 __attribute__((ext_vector_type(8)));
typedef _Float16 f16x8 __attribute__((ext_vector_type(8)));
typedef float f32x4 __attribute__((ext_vector_type(4)));

#define NSEQ 2048
#define CDIM 512

// ---- ws layout (bytes) ----
#define WS_FLAGS   0         // int[3]: x dtype, w dtype, const 0
#define WS_BPB     1024
#define WS_WPB     4096
#define WS_WEC     532480    // We_q, We_k (512x1536 bf16 each)
#define WS_WECT    3678208   // We_v^T (1536x512 bf16)
#define WS_W1T     5251072
#define WS_W3R     6823936
#define WS_BASE    11542528  // adaptive region: Sb | slotA | (optional) xb

__device__ __forceinline__ float rdf(const void* p, long i, int f) {
  if (f == 1) return ((const float*)p)[i];
  if (f == 2) return (float)((const _Float16*)p)[i];
  return (float)((const bf16*)p)[i];
}

__device__ __forceinline__ void gl_lds16(const bf16* g, bf16* l) {
  __builtin_amdgcn_global_load_lds(
      (__attribute__((address_space(1))) void*)g,
      (__attribute__((address_space(3))) void*)l, 16, 0, 0);
}

__device__ __forceinline__ void stage_one(const void* gb, long eoff, int dt,
                                          bf16* ldst)
{
  if (dt == 1) {
    const float* g = (const float*)gb + eoff;
    const float4 u0 = *(const float4*)g;
    const float4 u1 = *(const float4*)(g + 4);
    bf16x8 t;
    t[0]=(bf16)u0.x; t[1]=(bf16)u0.y; t[2]=(bf16)u0.z; t[3]=(bf16)u0.w;
    t[4]=(bf16)u1.x; t[5]=(bf16)u1.y; t[6]=(bf16)u1.z; t[7]=(bf16)u1.w;
    *(bf16x8*)ldst = t;
  } else if (dt == 2) {
    const f16x8 h = *(const f16x8*)((const _Float16*)gb + eoff);
    bf16x8 t;
#pragma unroll
    for (int j = 0; j < 8; ++j) t[j] = (bf16)(float)h[j];
    *(bf16x8*)ldst = t;
  } else {
    gl_lds16((const bf16*)gb + eoff, ldst);
  }
}

// 3-way dtype detect (0 bf16, 1 f32, 2 fp16); flags[2] <- 0.
__global__ __launch_bounds__(256)
void detect2(const unsigned short* __restrict__ a,
             const unsigned short* __restrict__ b, int* __restrict__ flags)
{
  const unsigned short* p = blockIdx.x ? b : a;
  __shared__ int chi, clo;
  if (threadIdx.x == 0) { chi = 0; clo = 0; }
  __syncthreads();
  int hi = 0, lo = 0;
  for (int i = threadIdx.x; i < 4096; i += 256) {
    const int e = (p[i] >> 7) & 0xff;
    hi += (e >= 141);
    lo += (e >= 1 && e <= 110);
  }
  atomicAdd(&chi, hi);
  atomicAdd(&clo, lo);
  __syncthreads();
  if (threadIdx.x == 0) {
    flags[blockIdx.x] = (chi > 8) ? 1 : ((clo > 100) ? 2 : 0);
    if (blockIdx.x == 0) flags[2] = 0;
  }
}

// x (any dtype) -> canonical bf16 copy, 8 elem/thread vectorized
__global__ __launch_bounds__(256)
void cvt_x8(const void* __restrict__ x, const int* __restrict__ flag,
            bf16* __restrict__ xb)
{
  const long i8 = (long)blockIdx.x * 256 + threadIdx.x;
  const int f = *flag;
  bf16x8 t;
  if (f == 1) {
    const float4* g = (const float4*)x + i8 * 2;
    const float4 u0 = g[0], u1 = g[1];
    t[0]=(bf16)u0.x; t[1]=(bf16)u0.y; t[2]=(bf16)u0.z; t[3]=(bf16)u0.w;
    t[4]=(bf16)u1.x; t[5]=(bf16)u1.y; t[6]=(bf16)u1.z; t[7]=(bf16)u1.w;
  } else if (f == 2) {
    const f16x8 h = ((const f16x8*)x)[i8];
#pragma unroll
    for (int j = 0; j < 8; ++j) t[j] = (bf16)(float)h[j];
  } else {
    t = ((const bf16x8*)x)[i8];
  }
  ((bf16x8*)xb)[i8] = t;
}

// ---------------------------------------------------------------------------
// Old 128^2 gemm (kept for weight prep and non-canonical fallback)
// C[m][n] = sum_k A[m][k] * B[n][k]   (K-contiguous operands, bf16 MFMA)
template<int AX3, int BX3, int EPI, int ZMODE>
__global__ __launch_bounds__(256)
void gemm_bt(const void* __restrict__ Abase, const void* __restrict__ Bbase,
             void* __restrict__ Cbase, const bf16* __restrict__ bias,
             const int* __restrict__ xflag, int zxb,
             int M, int Nd, int K, int lda, int ldb, int ldc,
             long zsA, long zsB, long zsC)
{
  __shared__ bf16 As[128 * 32];
  __shared__ bf16 Bs[128 * 32];
  const int z = blockIdx.z;
  const int xdt = (AX3 || BX3) ? *xflag : 0;
  long Aoff, Boff; char* CB;
  if (ZMODE == 1) {
    const int g = z / 3, t = z - g * 3;
    Aoff = (long)z * 262144;
    Boff = (long)g * 262144;
    CB = (char*)Cbase + ((long)g * (512 * 1536) + t * 512) * 2;
  } else {
    Aoff = AX3 ? 0 : (long)z * zsA;
    Boff = BX3 ? 0 : (long)z * zsB;
    CB = (char*)Cbase + (long)z * zsC * (EPI == 2 ? 4 : 2);
  }
  const int m0 = blockIdx.y * 128;
  const int n0 = blockIdx.x * 128;
  const int tid = threadIdx.x;
  const int lane = tid & 63;
  const int w = tid >> 6;
  const int wr = (w >> 1) * 64;
  const int wc = (w & 1) * 64;

  f32x4 acc[4][4];
  const f32x4 zero = {0.f, 0.f, 0.f, 0.f};
#pragma unroll
  for (int i = 0; i < 4; ++i)
#pragma unroll
    for (int j = 0; j < 4; ++j) acc[i][j] = zero;

  for (int k0 = 0; k0 < K; k0 += 32) {
#pragma unroll
    for (int it = 0; it < 2; ++it) {
      const int f  = (it * 256 + tid) * 16;
      const int r  = f >> 6;
      const int cb = (f & 63) >> 1;
      long ea, eb;
      if (AX3) {
        const int tau = k0 >> 9;
        ea = (long)(z + zxb) * zsA +
             (long)((m0 + r + tau - 1) & (NSEQ - 1)) * CDIM + (k0 & 511) + cb;
      } else {
        ea = Aoff + (long)(m0 + r) * lda + k0 + cb;
      }
      stage_one(Abase, ea, AX3 ? xdt : 0, (bf16*)((char*)As + f));
      if (BX3) {
        const int tau = k0 >> 9;
        eb = (long)(z + zxb) * zsB +
             (long)((n0 + r + tau - 1) & (NSEQ - 1)) * CDIM + (k0 & 511) + cb;
      } else {
        eb = Boff + (long)(n0 + r) * ldb + k0 + cb;
      }
      stage_one(Bbase, eb, BX3 ? xdt : 0, (bf16*)((char*)Bs + f));
    }
    __syncthreads();

    const int qb = (lane >> 4) * 16;
    const int fr = lane & 15;
    bf16x8 af[4], bfr[4];
#pragma unroll
    for (int i = 0; i < 4; ++i)
      af[i] = *(const bf16x8*)((const char*)As + (wr + i * 16 + fr) * 64 + qb);
#pragma unroll
    for (int j = 0; j < 4; ++j)
      bfr[j] = *(const bf16x8*)((const char*)Bs + (wc + j * 16 + fr) * 64 + qb);
#pragma unroll
    for (int i = 0; i < 4; ++i)
#pragma unroll
      for (int j = 0; j < 4; ++j)
        acc[i][j] = __builtin_amdgcn_mfma_f32_16x16x32_bf16(af[i], bfr[j], acc[i][j], 0, 0, 0);
    __syncthreads();
  }

  const int qa4 = (lane >> 4) * 4;
  const int cn = lane & 15;
#pragma unroll
  for (int i = 0; i < 4; ++i) {
#pragma unroll
    for (int j = 0; j < 4; ++j) {
      const int gn = n0 + wc + j * 16 + cn;
      const float bv = (EPI == 2) ? (float)bias[gn] : 0.f;
#pragma unroll
      for (int r = 0; r < 4; ++r) {
        const long gm = m0 + wr + i * 16 + qa4 + r;
        if (EPI == 2) ((float*)CB)[gm * ldc + gn] = acc[i][j][r] + bv;
        else          ((bf16*)CB)[gm * ldc + gn] = (bf16)acc[i][j][r];
      }
    }
  }
}

// ---------------------------------------------------------------------------
// Fragment-order staging of a 256x32 bf16 operand tile (2 gl_lds/thread,
// 512 threads). LDS slot l of each 16-row group holds (row l&15, k-chunk
// l>>4) -> every fragment ds_read_b128 is base + lane*16 (contiguous 1 KiB
// wave read, 0 bank conflicts); global source stays 64B-per-row coalesced.
template<int X3>
__device__ __forceinline__ void stage32(const bf16* __restrict__ gb, long zoff,
                                        int r0, int k0, int ld,
                                        char* ldsb, int tid)
{
#pragma unroll
  for (int is = 0; is < 2; ++is) {
    const int c = is * 512 + tid;
    const int g = c >> 6;
    const int l = c & 63;
    const int r = g * 16 + (l & 15);
    const int kb = l >> 4;
    long e;
    if (X3) {
      const int tau = k0 >> 9;
      const int rg = (r0 + r + tau - 1) & (NSEQ - 1);
      e = zoff + (long)rg * CDIM + ((k0 & 511) + kb * 8);
    } else {
      e = zoff + (long)(r0 + r) * ld + k0 + kb * 8;
    }
    gl_lds16(gb + e, (bf16*)(ldsb + c * 16));
  }
}

// Same layout for a 128x32 tile with 256 threads (gemm4p).
__device__ __forceinline__ void stage16(const bf16* __restrict__ gb, long zoff,
                                        int r0, int k0, int ld,
                                        char* ldsb, int tid)
{
#pragma unroll
  for (int is = 0; is < 2; ++is) {
    const int c = is * 256 + tid;       // slot 0..511
    const int g = c >> 6;               // 16-row group 0..7
    const int l = c & 63;
    const int r = g * 16 + (l & 15);
    const int kb = l >> 4;
    const long e = zoff + (long)(r0 + r) * ld + k0 + kb * 8;
    gl_lds16(gb + e, (bf16*)(ldsb + c * 16));
  }
}

// ---------------------------------------------------------------------------
// R2 kernel: 256^2, BK=32, 64 KiB static LDS double-buffer (FALLBACK path).
template<int AX3, int BX3, int EPI>
__global__ __launch_bounds__(512)
void gemm8(const bf16* __restrict__ Ab, const bf16* __restrict__ Bb,
           void* __restrict__ Cbase, const bf16* __restrict__ bias,
           int zxb, int M, int Nd, int K, int lda, int ldb, int ldc,
           long zsA, long zsB, long zsC)
{
  __shared__ char smem[65536];
  const int z = blockIdx.z;
  const long Aoff = (long)(AX3 ? (z + zxb) : z) * zsA;
  const long Boff = (long)(BX3 ? (z + zxb) : z) * zsB;
  char* CB = (char*)Cbase + (long)z * zsC * (EPI == 2 ? 4 : 2);
  const int m0 = blockIdx.y * 256;
  const int n0 = blockIdx.x * 256;
  const int tid = threadIdx.x;
  const int lane = tid & 63;
  const int w = tid >> 6, wm = w >> 2, wn = w & 3;
  const int fro = lane * 16;

  f32x4 acc[8][4];
  const f32x4 zero = {0.f, 0.f, 0.f, 0.f};
#pragma unroll
  for (int i = 0; i < 8; ++i)
#pragma unroll
    for (int j = 0; j < 4; ++j) acc[i][j] = zero;

  const int KT = K >> 5;
  stage32<AX3>(Ab, Aoff, m0, 0, lda, smem, tid);
  stage32<BX3>(Bb, Boff, n0, 0, ldb, smem + 16384, tid);
  __syncthreads();

  for (int T = 0; T < KT; ++T) {
    const int cur = T & 1;
    const char* sA = smem + cur * 32768;
    const char* sB = sA + 16384;
    if (T + 1 < KT) {
      char* nb = smem + (cur ^ 1) * 32768;
      const int k1 = (T + 1) << 5;
      stage32<AX3>(Ab, Aoff, m0, k1, lda, nb, tid);
      stage32<BX3>(Bb, Boff, n0, k1, ldb, nb + 16384, tid);
    }
    bf16x8 bfr[4];
#pragma unroll
    for (int j = 0; j < 4; ++j)
      bfr[j] = *(const bf16x8*)(sB + (wn * 4 + j) * 1024 + fro);
#pragma unroll
    for (int h = 0; h < 2; ++h) {
      bf16x8 af[4];
#pragma unroll
      for (int i2 = 0; i2 < 4; ++i2)
        af[i2] = *(const bf16x8*)(sA + (wm * 8 + h * 4 + i2) * 1024 + fro);
      __builtin_amdgcn_s_setprio(1);
#pragma unroll
      for (int i2 = 0; i2 < 4; ++i2)
#pragma unroll
        for (int j = 0; j < 4; ++j)
          acc[h * 4 + i2][j] = __builtin_amdgcn_mfma_f32_16x16x32_bf16(
              af[i2], bfr[j], acc[h * 4 + i2][j], 0, 0, 0);
      __builtin_amdgcn_s_setprio(0);
      if (h == 0) __builtin_amdgcn_s_barrier();
    }
    __syncthreads();
  }

  const int lr = lane & 15, lk = lane >> 4;
#pragma unroll
  for (int i = 0; i < 8; ++i) {
#pragma unroll
    for (int j = 0; j < 4; ++j) {
      const int gn = n0 + wn * 64 + j * 16 + lr;
      const float bv = (EPI == 2) ? (float)bias[gn] : 0.f;
#pragma unroll
      for (int r = 0; r < 4; ++r) {
        const long gm = m0 + wm * 128 + i * 16 + lk * 4 + r;
        if (EPI == 2) ((float*)CB)[gm * ldc + gn] = acc[i][j][r] + bv;
        else          ((bf16*)CB)[gm * ldc + gn] = (bf16)acc[i][j][r];
      }
    }
  }
}

// ---------------------------------------------------------------------------
// gemm8p (R3, measured best for the big gemms): 256^2, BK=32, 3 x 32 KiB
// dynamic LDS, depth-2 counted-vmcnt pipeline + mid-tile phase lock.
template<int AX3, int BX3, int EPI>
__global__ __launch_bounds__(512)
void gemm8p(const bf16* __restrict__ Ab, const bf16* __restrict__ Bb,
            void* __restrict__ Cbase, const bf16* __restrict__ bias,
            int zxb, int M, int Nd, int K, int lda, int ldb, int ldc,
            long zsA, long zsB, long zsC)
{
  extern __shared__ char smem[];   // 3 x 32768
  const int gx = gridDim.x, gy = gridDim.y;
  const int total = gx * gy * gridDim.z;
  const int lin = blockIdx.x + gx * (blockIdx.y + gy * blockIdx.z);
  const int q = total >> 3, r = total & 7;
  const int xcd = lin & 7, kq = lin >> 3;
  int swz = (xcd < r ? xcd * (q + 1) : r * (q + 1) + (xcd - r) * q) + kq;
  const int ny = swz % gy; swz /= gy;
  const int nx = swz % gx;
  const int z  = swz / gx;

  const long Aoff = (long)(AX3 ? (z + zxb) : z) * zsA;
  const long Boff = (long)(BX3 ? (z + zxb) : z) * zsB;
  char* CB = (char*)Cbase + (long)z * zsC * (EPI == 2 ? 4 : 2);
  const int m0 = ny * 256;
  const int n0 = nx * 256;
  const int tid = threadIdx.x;
  const int lane = tid & 63;
  const int w = tid >> 6, wm = w >> 2, wn = w & 3;
  const int fro = lane * 16;

  f32x4 acc[8][4];
  const f32x4 zero = {0.f, 0.f, 0.f, 0.f};
#pragma unroll
  for (int i = 0; i < 8; ++i)
#pragma unroll
    for (int j = 0; j < 4; ++j) acc[i][j] = zero;

  const int KT = K >> 5;

  stage32<AX3>(Ab, Aoff, m0, 0, lda, smem, tid);
  stage32<BX3>(Bb, Boff, n0, 0, ldb, smem + 16384, tid);
  stage32<AX3>(Ab, Aoff, m0, 32, lda, smem + 32768, tid);
  stage32<BX3>(Bb, Boff, n0, 32, ldb, smem + 32768 + 16384, tid);

  for (int T = 0; T < KT; ++T) {
    if (T + 1 < KT) asm volatile("s_waitcnt vmcnt(4)" ::: "memory");
    else            asm volatile("s_waitcnt vmcnt(0)" ::: "memory");
    __builtin_amdgcn_s_barrier();

    if (T + 2 < KT) {
      char* nb = smem + ((T + 2) % 3) * 32768;
      const int k2 = (T + 2) << 5;
      stage32<AX3>(Ab, Aoff, m0, k2, lda, nb, tid);
      stage32<BX3>(Bb, Boff, n0, k2, ldb, nb + 16384, tid);
    }

    const char* sA = smem + (T % 3) * 32768;
    const char* sB = sA + 16384;
    bf16x8 bfr[4];
#pragma unroll
    for (int j = 0; j < 4; ++j)
      bfr[j] = *(const bf16x8*)(sB + (wn * 4 + j) * 1024 + fro);
#pragma unroll
    for (int h = 0; h < 2; ++h) {
      bf16x8 af[4];
#pragma unroll
      for (int i2 = 0; i2 < 4; ++i2)
        af[i2] = *(const bf16x8*)(sA + (wm * 8 + h * 4 + i2) * 1024 + fro);
      __builtin_amdgcn_s_setprio(1);
#pragma unroll
      for (int i2 = 0; i2 < 4; ++i2)
#pragma unroll
        for (int j = 0; j < 4; ++j)
          acc[h * 4 + i2][j] = __builtin_amdgcn_mfma_f32_16x16x32_bf16(
              af[i2], bfr[j], acc[h * 4 + i2][j], 0, 0, 0);
      __builtin_amdgcn_s_setprio(0);
      if (h == 0) __builtin_amdgcn_s_barrier();
    }
  }

  const int lr = lane & 15, lk = lane >> 4;
#pragma unroll
  for (int i = 0; i < 8; ++i) {
#pragma unroll
    for (int j = 0; j < 4; ++j) {
      const int gn = n0 + wn * 64 + j * 16 + lr;
      const float bv = (EPI == 2) ? (float)bias[gn] : 0.f;
#pragma unroll
      for (int r2 = 0; r2 < 4; ++r2) {
        const long gm = m0 + wm * 128 + i * 16 + lk * 4 + r2;
        if (EPI == 2) ((float*)CB)[gm * ldc + gn] = acc[i][j][r2] + bv;
        else          ((bf16*)CB)[gm * ldc + gn] = (bf16)acc[i][j][r2];
      }
    }
  }
}

// ---------------------------------------------------------------------------
// gemm4p: the SAME R3 pipeline at 128^2 geometry for At/U (full-CU grids,
// 3 blocks/CU occupancy). 4 waves (2x2, 64x64 each), BK=32, 3 x 16 KiB
// STATIC LDS ring, depth-2 counted vmcnt(4), mid-tile phase-lock barrier,
// fragment-order LDS (0 bank conflicts). Canonical bf16 operands only.
template<int EPI>
__global__ __launch_bounds__(256)
void gemm4p(const bf16* __restrict__ Ab, const bf16* __restrict__ Bb,
            void* __restrict__ Cbase, const bf16* __restrict__ bias,
            int M, int Nd, int K, int lda, int ldb, int ldc,
            long zsA, long zsB, long zsC)
{
  __shared__ char smem[49152];   // 3 x 16384
  const int gx = gridDim.x, gy = gridDim.y;
  const int total = gx * gy * gridDim.z;
  const int lin = blockIdx.x + gx * (blockIdx.y + gy * blockIdx.z);
  const int q = total >> 3, r = total & 7;
  const int xcd = lin & 7, kq = lin >> 3;
  int swz = (xcd < r ? xcd * (q + 1) : r * (q + 1) + (xcd - r) * q) + kq;
  const int ny = swz % gy; swz /= gy;
  const int nx = swz % gx;
  const int z  = swz / gx;

  const long Aoff = (long)z * zsA;
  const long Boff = (long)z * zsB;
  char* CB = (char*)Cbase + (long)z * zsC * (EPI == 2 ? 4 : 2);
  const int m0 = ny * 128;
  const int n0 = nx * 128;
  const int tid = threadIdx.x;
  const int lane = tid & 63;
  const int w = tid >> 6;
  const int wr = (w >> 1) * 64, wc = (w & 1) * 64;
  const int fro = lane * 16;
  const int ga = wr >> 4, gb2 = wc >> 4;   // 16-row group bases

  f32x4 acc[4][4];
  const f32x4 zero = {0.f, 0.f, 0.f, 0.f};
#pragma unroll
  for (int i = 0; i < 4; ++i)
#pragma unroll
    for (int j = 0; j < 4; ++j) acc[i][j] = zero;

  const int KT = K >> 5;   // >= 16 for all uses

  stage16(Ab, Aoff, m0, 0, lda, smem, tid);
  stage16(Bb, Boff, n0, 0, ldb, smem + 8192, tid);
  stage16(Ab, Aoff, m0, 32, lda, smem + 16384, tid);
  stage16(Bb, Boff, n0, 32, ldb, smem + 16384 + 8192, tid);

  for (int T = 0; T < KT; ++T) {
    if (T + 1 < KT) asm volatile("s_waitcnt vmcnt(4)" ::: "memory");
    else            asm volatile("s_waitcnt vmcnt(0)" ::: "memory");
    __builtin_amdgcn_s_barrier();

    if (T + 2 < KT) {
      char* nb = smem + ((T + 2) % 3) * 16384;
      const int k2 = (T + 2) << 5;
      stage16(Ab, Aoff, m0, k2, lda, nb, tid);
      stage16(Bb, Boff, n0, k2, ldb, nb + 8192, tid);
    }

    const char* sA = smem + (T % 3) * 16384;
    const char* sB = sA + 8192;
    bf16x8 bfr[4];
#pragma unroll
    for (int j = 0; j < 4; ++j)
      bfr[j] = *(const bf16x8*)(sB + (gb2 + j) * 1024 + fro);
#pragma unroll
    for (int h = 0; h < 2; ++h) {
      bf16x8 af[2];
#pragma unroll
      for (int i2 = 0; i2 < 2; ++i2)
        af[i2] = *(const bf16x8*)(sA + (ga + h * 2 + i2) * 1024 + fro);
      __builtin_amdgcn_s_setprio(1);
#pragma unroll
      for (int i2 = 0; i2 < 2; ++i2)
#pragma unroll
        for (int j = 0; j < 4; ++j)
          acc[h * 2 + i2][j] = __builtin_amdgcn_mfma_f32_16x16x32_bf16(
              af[i2], bfr[j], acc[h * 2 + i2][j], 0, 0, 0);
      __builtin_amdgcn_s_setprio(0);
      if (h == 0) __builtin_amdgcn_s_barrier();
    }
  }

  const int qa4 = (lane >> 4) * 4;
  const int cn = lane & 15;
#pragma unroll
  for (int i = 0; i < 4; ++i) {
#pragma unroll
    for (int j = 0; j < 4; ++j) {
      const int gn = n0 + wc + j * 16 + cn;
      const float bv = (EPI == 2) ? (float)bias[gn] : 0.f;
#pragma unroll
      for (int r2 = 0; r2 < 4; ++r2) {
        const long gm = m0 + wr + i * 16 + qa4 + r2;
        if (EPI == 2) ((float*)CB)[gm * ldc + gn] = acc[i][j][r2] + bv;
        else          ((bf16*)CB)[gm * ldc + gn] = (bf16)acc[i][j][r2];
      }
    }
  }
}

// ---------------------------------------------------------------------------
// w1t[g][a][b] = w1_g[b][a]; w3r[g*3+t][o][i] = w3_g[o][i][t]; wp/bp canonical.
__global__ __launch_bounds__(256)
void repack(const void* __restrict__ w1q, const void* __restrict__ w3q,
            const void* __restrict__ w1k, const void* __restrict__ w3k,
            const void* __restrict__ w1v, const void* __restrict__ w3v,
            const void* __restrict__ wp, const void* __restrict__ bpr,
            const int* __restrict__ flag,
            bf16* __restrict__ w1t, bf16* __restrict__ w3r,
            bf16* __restrict__ wpb, bf16* __restrict__ bpb)
{
  const int isf = *flag;
  const int g = blockIdx.z;
  const void* w1 = (g == 0) ? w1q : (g == 1) ? w1k : w1v;
  const void* w3 = (g == 0) ? w3q : (g == 1) ? w3k : w3v;
  const int idx = blockIdx.x * 256 + threadIdx.x;
  const int o = idx >> 9, c = idx & 511;
  w1t[g * 262144 + idx] = (bf16)rdf(w1, (long)c * 512 + o, isf);
#pragma unroll
  for (int t = 0; t < 3; ++t)
    w3r[(g * 3 + t) * 262144 + idx] = (bf16)rdf(w3, ((long)o * 512 + c) * 3 + t, isf);
  if (g == 0) {
    wpb[idx] = (bf16)rdf(wp, idx, isf);
    if (idx < 512) bpb[idx] = (bf16)rdf(bpr, idx, isf);
  }
}

// Column softmax over d on At[b][d][c] (scale 1/512), split into two
// 128-d-slice passes for 4x block parallelism. P[z][slice][c] = (m, l).
__global__ __launch_bounds__(256)
void softmax_p1(const bf16* __restrict__ S, float2* __restrict__ P)
{
  const int z = blockIdx.z;
  const int c = blockIdx.x * 256 + threadIdx.x;
  const int d0 = blockIdx.y * 128;
  const bf16* s = S + (long)z * 262144 + c;
  const float sc = 1.0f / 512.0f;
  float m = -3.4e38f, l = 0.f;
  for (int d = d0; d < d0 + 128; ++d) {
    const float v = (float)s[d * 512] * sc;
    const float nm = fmaxf(m, v);
    l = l * __expf(m - nm) + __expf(v - nm);
    m = nm;
  }
  P[((long)z * 4 + blockIdx.y) * 512 + c] = make_float2(m, l);
}

__global__ __launch_bounds__(256)
void softmax_p2(bf16* __restrict__ S, const float2* __restrict__ P)
{
  const int z = blockIdx.z;
  const int c = blockIdx.x * 256 + threadIdx.x;
  const int d0 = blockIdx.y * 128;
  float m = -3.4e38f, l = 0.f;
#pragma unroll
  for (int i = 0; i < 4; ++i) {
    const float2 p = P[((long)z * 4 + i) * 512 + c];
    const float nm = fmaxf(m, p.x);
    l = l * __expf(m - nm) + p.y * __expf(p.x - nm);
    m = nm;
  }
  const float inv = 1.0f / l;
  bf16* s = S + (long)z * 262144 + c;
  const float sc = 1.0f / 512.0f;
  for (int d = d0; d < d0 + 128; ++d) {
    const float v = (float)s[d * 512] * sc;
    s[d * 512] = (bf16)(__expf(v - m) * inv);
  }
}

extern "C" void kernel_launch(void* const* d_in, const int* in_sizes, int n_in,
                              void* d_out, int out_size, void* d_ws, size_t ws_size,
                              hipStream_t stream)
{
  // ---- resolve input roles from in_sizes (robust to ordering) ----
  long smax = -1, smin = (long)1 << 62;
  for (int i = 0; i < n_in; ++i) {
    const long s = in_sizes[i];
    if (s > smax) smax = s;
    if (s < smin) smin = s;
  }
  long s3 = -1;
  for (int i = 0; i < n_in; ++i) {
    const long s = in_sizes[i];
    if (s < smax && s > s3) s3 = s;
  }
  int xi = -1, bi = -1, w1i[8], n1 = 0, w3i[8], n3 = 0;
  for (int i = 0; i < n_in; ++i) {
    const long s = in_sizes[i];
    if (s == smax && xi < 0) xi = i;
    else if (s == smin && bi < 0) bi = i;
    else if (s == s3) { if (n3 < 8) w3i[n3++] = i; }
    else             { if (n1 < 8) w1i[n1++] = i; }
  }
  const void *x, *w1q, *w3q, *w1k, *w3k, *w1v, *w3v, *wp, *bp;
  if (xi >= 0 && bi >= 0 && n1 >= 4 && n3 >= 3) {
    x = d_in[xi]; bp = d_in[bi];
    w1q = d_in[w1i[0]]; w1k = d_in[w1i[1]]; w1v = d_in[w1i[2]]; wp = d_in[w1i[3]];
    w3q = d_in[w3i[0]]; w3k = d_in[w3i[1]]; w3v = d_in[w3i[2]];
  } else {
    x = d_in[0]; w1q = d_in[1]; w3q = d_in[2]; w1k = d_in[3]; w3k = d_in[4];
    w1v = d_in[5]; w3v = d_in[6]; wp = d_in[7]; bp = d_in[8];
  }
  float* out = (float*)d_out;  // reference output dtype = float32

  char* ws = (char*)d_ws;
  int*  flags = (int*)(ws + WS_FLAGS);
  bf16* bpb  = (bf16*)(ws + WS_BPB);
  bf16* wpb  = (bf16*)(ws + WS_WPB);
  bf16* wec  = (bf16*)(ws + WS_WEC);
  bf16* wecT = (bf16*)(ws + WS_WECT);
  bf16* w1t  = (bf16*)(ws + WS_W1T);
  bf16* w3r  = (bf16*)(ws + WS_W3R);

  // ---- adaptive: batch chunk NB + optional bf16-x staging copy ----
  int NB = 16, conv = 1;
  while (NB >= 1 && WS_BASE + (size_t)NB * 2621440 + 33554432 > ws_size) NB >>= 1;
  if (NB == 0) {
    conv = 0; NB = 16;
    while (NB > 1 && WS_BASE + (size_t)NB * 2621440 > ws_size) NB >>= 1;
  }
  bf16* Sb    = (bf16*)(ws + WS_BASE);
  bf16* slotA = (bf16*)(ws + WS_BASE + (size_t)NB * 524288);
  bf16* U     = slotA;
  bf16* Wfin  = slotA + (size_t)NB * 262144;
  bf16* xb    = (bf16*)(ws + WS_BASE + (size_t)NB * 2621440);
  float2* Pp  = (float2*)slotA;   // softmax partials: free while Q consumed

  const dim3 blk(256, 1, 1);
  const dim3 blk8(512, 1, 1);

  // opt-in to 96 KiB dynamic LDS for gemm8p; graceful fallback if refused
  bool ok9 = true;
  {
    hipError_t e;
    e = hipFuncSetAttribute(reinterpret_cast<const void*>(&gemm8p<0, 1, 0>),
                            hipFuncAttributeMaxDynamicSharedMemorySize, 98304);
    ok9 = ok9 && (e == hipSuccess);
    e = hipFuncSetAttribute(reinterpret_cast<const void*>(&gemm8p<0, 0, 0>),
                            hipFuncAttributeMaxDynamicSharedMemorySize, 98304);
    ok9 = ok9 && (e == hipSuccess);
    e = hipFuncSetAttribute(reinterpret_cast<const void*>(&gemm8p<1, 0, 2>),
                            hipFuncAttributeMaxDynamicSharedMemorySize, 98304);
    ok9 = ok9 && (e == hipSuccess);
  }

  // 1. dtype detect
  detect2<<<dim3(2, 1, 1), blk, 0, stream>>>(
      (const unsigned short*)x, (const unsigned short*)w1q, flags);

  // 2. canonical bf16 x copy (keeps the global_load_lds fast path)
  const void* xu = x;
  const int* xflag = flags;
  if (conv) {
    cvt_x8<<<dim3(8192, 1, 1), blk, 0, stream>>>(x, flags, xb);
    xu = xb;
    xflag = flags + 2;  // const 0 -> bf16 async staging
  }

  // 3. weights: repack + effective conv weights
  repack<<<dim3(1024, 1, 3), blk, 0, stream>>>(w1q, w3q, w1k, w3k, w1v, w3v,
                                               wp, bp, flags + 1,
                                               w1t, w3r, wpb, bpb);
  gemm_bt<0, 0, 0, 1><<<dim3(4, 4, 6), blk, 0, stream>>>(
      w3r, w1t, wec, nullptr, nullptr, 0, 512, 512, 512, 512, 512, 1536, 0, 0, 0);
  gemm_bt<0, 0, 0, 0><<<dim3(4, 4, 3), blk, 0, stream>>>(
      w1t + 2 * 262144, w3r + 6 * 262144, wecT, nullptr, nullptr, 0,
      512, 512, 512, 512, 512, 512, 0, 262144, 262144);

  // 4. attention pipeline, batch-chunked
  for (int b0 = 0; b0 < 16; b0 += NB) {
    char* outc = (char*)out + (size_t)b0 * 2048 * 512 * 4;
    if (conv) {
      // QK merged: [1024][2048] bf16 per batch parks in this chunk's f32 out
      // region (4 MB each, exact fit). Overwritten by 'out' only after At.
      bf16* QKc = (bf16*)outc;
      if (ok9) {
        gemm8p<0, 1, 0><<<dim3(8, 4, NB), blk8, 98304, stream>>>(
            wec, (const bf16*)xu, QKc, nullptr, b0,
            1024, 2048, 1536, 1536, 0, 2048,
            0, (long)NSEQ * CDIM, (long)1024 * 2048);
      } else {
        gemm8<0, 1, 0><<<dim3(8, 4, NB), blk8, 0, stream>>>(
            wec, (const bf16*)xu, QKc, nullptr, b0,
            1024, 2048, 1536, 1536, 0, 2048,
            0, (long)NSEQ * CDIM, (long)1024 * 2048);
      }
      gemm4p<0><<<dim3(4, 4, NB), blk, 0, stream>>>(                // At[d][c]
          QKc + (long)512 * 2048, QKc, Sb, nullptr,
          512, 512, 2048, 2048, 2048, 512,
          (long)1024 * 2048, (long)1024 * 2048, (long)512 * 512);
      softmax_p1<<<dim3(2, 4, NB), blk, 0, stream>>>(Sb, Pp);
      softmax_p2<<<dim3(2, 4, NB), blk, 0, stream>>>(Sb, Pp);
      gemm4p<0><<<dim3(4, 4, NB), blk, 0, stream>>>(                // U[o][d]
          wpb, Sb, U, nullptr,
          512, 512, 512, 512, 512, 512,
          0, (long)512 * 512, (long)512 * 512);
      if (ok9) {
        gemm8p<0, 0, 0><<<dim3(6, 2, NB), blk8, 98304, stream>>>(   // Wfin[o][k]
            U, wecT, Wfin, nullptr, 0, 512, 1536, 512, 512, 512, 1536,
            (long)512 * 512, 0, (long)512 * 1536);
        gemm8p<1, 0, 2><<<dim3(2, 8, NB), blk8, 98304, stream>>>(   // out f32+bias
            (const bf16*)xu, Wfin, outc, bpb, b0,
            2048, 512, 1536, 0, 1536, 512,
            (long)NSEQ * CDIM, (long)512 * 1536, (long)2048 * 512);
      } else {
        gemm8<0, 0, 0><<<dim3(6, 2, NB), blk8, 0, stream>>>(
            U, wecT, Wfin, nullptr, 0, 512, 1536, 512, 512, 512, 1536,
            (long)512 * 512, 0, (long)512 * 1536);
        gemm8<1, 0, 2><<<dim3(2, 8, NB), blk8, 0, stream>>>(
            (const bf16*)xu, Wfin, outc, bpb, b0,
            2048, 512, 1536, 0, 1536, 512,
            (long)NSEQ * CDIM, (long)512 * 1536, (long)2048 * 512);
      }
    } else {
      // fallback: original 128^2 path with inline dtype conversion
      bf16* Kc = (bf16*)outc;
      gemm_bt<0, 1, 0, 0><<<dim3(16, 4, NB), blk, 0, stream>>>(     // Q[c][n]
          wec, xu, slotA, nullptr, xflag, b0, 512, 2048, 1536, 1536, 0, 2048,
          0, (long)NSEQ * CDIM, (long)512 * 2048);
      gemm_bt<0, 1, 0, 0><<<dim3(16, 4, NB), blk, 0, stream>>>(     // K[d][n]
          wec + 512 * 1536, xu, Kc, nullptr, xflag, b0, 512, 2048, 1536, 1536, 0, 2048,
          0, (long)NSEQ * CDIM, (long)512 * 2048);
      gemm_bt<0, 0, 0, 0><<<dim3(4, 4, NB), blk, 0, stream>>>(      // At[d][c]
          Kc, slotA, Sb, nullptr, nullptr, 0, 512, 512, 2048, 2048, 2048, 512,
          (long)512 * 2048, (long)512 * 2048, (long)512 * 512);
      softmax_p1<<<dim3(2, 4, NB), blk, 0, stream>>>(Sb, Pp);
      softmax_p2<<<dim3(2, 4, NB), blk, 0, stream>>>(Sb, Pp);
      gemm_bt<0, 0, 0, 0><<<dim3(4, 4, NB), blk, 0, stream>>>(      // U[o][d]
          wpb, Sb, U, nullptr, nullptr, 0, 512, 512, 512, 512, 512, 512,
          0, (long)512 * 512, (long)512 * 512);
      gemm_bt<0, 0, 0, 0><<<dim3(12, 4, NB), blk, 0, stream>>>(     // Wfin[o][k]
          U, wecT, Wfin, nullptr, nullptr, 0, 512, 1536, 512, 512, 512, 1536,
          (long)512 * 512, 0, (long)512 * 1536);
      gemm_bt<1, 0, 2, 0><<<dim3(4, 16, NB), blk, 0, stream>>>(     // out[n][o] f32+bias
          xu, Wfin, outc, bpb, xflag, b0,
          2048, 512, 1536, 0, 1536, 512,
          (long)NSEQ * CDIM, (long)512 * 1536, (long)2048 * 512);
    }
  }
}